// Round 8
// baseline (228.643 us; speedup 1.0000x reference)
//
#include <hip/hip_runtime.h>
#include <hip/hip_bf16.h>
#include <cmath>

typedef float f32x4 __attribute__((ext_vector_type(4)));
typedef float f32x16 __attribute__((ext_vector_type(16)));
typedef __bf16 bf16x2 __attribute__((ext_vector_type(2)));
typedef __bf16 bf16x4 __attribute__((ext_vector_type(4)));
typedef __bf16 bf16x8 __attribute__((ext_vector_type(8)));

#define C_IN 384
#define C_OUT 384
#define SPB 4096      // spatial per batch image (64*64)
#define NPIX 131072   // 32 * 4096 total pixels
#define BP 64         // pixels per GEMM block
#define LDK 392       // fallback kernel's padded Xs row
#define ROW2 34       // gemm LDS row stride in bf16 (17 words: bijective banks)

// ---------------------------------------------------------------------------
// prep: Wp[o][c] = bf16(W[o][c]*gamma[c])  (row-major, for fallback)
//       Wt tiled: Wt[((o>>5)*48 + (c>>3))*256 + (o&31)*8 + (c&7)]  (for gemm)
//       t1[o] = sum_c float(Wp[o][c]);  t2[o] = sum_c beta[c]*W[o][c] + b[o]
// ---------------------------------------------------------------------------
__global__ __launch_bounds__(128) void ppl_prep_kernel(const float* __restrict__ W,
                                                       const float* __restrict__ gamma,
                                                       const float* __restrict__ beta,
                                                       const float* __restrict__ bias,
                                                       __bf16* __restrict__ Wp,
                                                       __bf16* __restrict__ Wt,
                                                       float* __restrict__ t1,
                                                       float* __restrict__ t2) {
  const int o = blockIdx.x;
  const int t = threadIdx.x;
  const float* row = W + o * C_IN;
  float s1 = 0.f, s2 = 0.f;
  for (int c = t; c < C_IN; c += 128) {
    const float w = row[c];
    const __bf16 wq = (__bf16)(w * gamma[c]);
    Wp[o * C_IN + c] = wq;
    Wt[(((size_t)(o >> 5) * 48 + (c >> 3)) << 8) + ((o & 31) << 3) + (c & 7)] = wq;
    s1 += (float)wq;
    s2 += beta[c] * w;
  }
#pragma unroll
  for (int off = 32; off > 0; off >>= 1) {
    s1 += __shfl_down(s1, off);
    s2 += __shfl_down(s2, off);
  }
  __shared__ float red[2][2];
  if ((t & 63) == 0) { red[t >> 6][0] = s1; red[t >> 6][1] = s2; }
  __syncthreads();
  if (t == 0) {
    t1[o] = red[0][0] + red[1][0];
    t2[o] = red[0][1] + red[1][1] + bias[o];
  }
}

// fast GELU: tanh-form via sigmoid; validated R2-R6 (absmax unchanged at 0.0156)
__device__ __forceinline__ float gelu_fast(float v) {
  const float u = 0.7978845608028654f * v * __builtin_fmaf(0.044715f * v, v, 1.0f);
  const float e = __expf(-2.0f * u);
  return v * __builtin_amdgcn_rcpf(1.0f + e);
}

// ---------------------------------------------------------------------------
// Pass 1 (unchanged, measured ~36 us): LN stats + bf16 cast, streaming.
// ---------------------------------------------------------------------------
__global__ __launch_bounds__(512) void ppl_stats_cast_kernel(const float* __restrict__ x,
                                                             __bf16* __restrict__ xb,
                                                             float* __restrict__ mu,
                                                             float* __restrict__ rs) {
  __shared__ float sS[8][256];
  __shared__ float sQ[8][256];
  const int tid = threadIdx.x;
  const int w = tid >> 6;
  const int lane = tid & 63;
  const int p0 = blockIdx.x * 256;
  const int b = p0 >> 12;
  const int s0 = p0 & 4095;
  const int c0 = w * 48;
  const float* xp = x + (((size_t)(b * C_IN + c0)) << 12) + s0 + 4 * lane;
  __bf16* xbp = xb + (((size_t)(b * C_IN + c0)) << 12) + s0 + 4 * lane;

  f32x4 ssv = {0.f, 0.f, 0.f, 0.f};
  f32x4 qqv = {0.f, 0.f, 0.f, 0.f};
#pragma unroll
  for (int i = 0; i < 48; i += 12) {
    f32x4 L[12];
#pragma unroll
    for (int j = 0; j < 12; ++j)
      L[j] = *reinterpret_cast<const f32x4*>(xp + ((size_t)(i + j) << 12));
#pragma unroll
    for (int j = 0; j < 12; ++j) {
      const f32x4 v = L[j];
      ssv += v;
      qqv += v * v;
      bf16x4 pk;
      pk[0] = (__bf16)v[0];
      pk[1] = (__bf16)v[1];
      pk[2] = (__bf16)v[2];
      pk[3] = (__bf16)v[3];
      *reinterpret_cast<bf16x4*>(xbp + ((size_t)(i + j) << 12)) = pk;
    }
  }
  *reinterpret_cast<f32x4*>(&sS[w][4 * lane]) = ssv;
  *reinterpret_cast<f32x4*>(&sQ[w][4 * lane]) = qqv;
  __syncthreads();
  if (tid < 256) {
    float st = 0.f, qt = 0.f;
#pragma unroll
    for (int r = 0; r < 8; ++r) {
      st += sS[r][tid];
      qt += sQ[r][tid];
    }
    const float m = st * (1.0f / C_IN);
    mu[p0 + tid] = m;
    rs[p0 + tid] = rsqrtf(qt * (1.0f / C_IN) - m * m + 1e-5f);
  }
}

// ---------------------------------------------------------------------------
// Pass 2 (gemm4): deep-pipelined GEMM + LN epilogue + GELU.
//   Block = 64 px x 192 outs; grid 4096.  Raw s_barrier (no vmcnt drain!):
//   global loads stay in flight across k-steps.  3-buffer LDS staging with
//   SLOAD issued 2 steps ahead; B frags (tiled Wt, L2) ping-ponged 1 step
//   ahead in registers.  Non-temporal output stores preserve xb's L3
//   residency for the 2nd o-group read.
// ---------------------------------------------------------------------------
__global__ __launch_bounds__(256, 4) void ppl_gemm4_kernel(const __bf16* __restrict__ xb,
                                                           const __bf16* __restrict__ Wt,
                                                           const float* __restrict__ mug,
                                                           const float* __restrict__ rsg,
                                                           const float* __restrict__ t1g,
                                                           const float* __restrict__ t2g,
                                                           float* __restrict__ out) {
  __shared__ __bf16 Xs[3][BP * ROW2];   // 3 x 4352 B
  __shared__ float mu_s[BP];
  __shared__ float rs_s[BP];

  const int tid = threadIdx.x;
  const int w = tid >> 6;
  const int lane = tid & 63;
  const int col = lane & 31;
  const int hi = lane >> 5;
  const int wm = w >> 1;          // px half (32 px)
  const int wn = w & 1;           // out half (96 outs)
  const int bid = blockIdx.x;
  const int og = bid & 1;         // out group (192 outs)
  const int pt = bid >> 1;
  const int p0 = pt * BP;
  const int b = p0 >> 12;
  const int s0 = p0 & 4095;

  if (tid < BP) {
    mu_s[tid] = mug[p0 + tid];
    rs_s[tid] = rsg[p0 + tid];
  }

  // staging map: v = px quad (4v..4v+3), c2 = channel pair (2c2, 2c2+1)
  const int v = tid & 15;
  const int c2 = tid >> 4;
  const __bf16* xsrc = xb + (((size_t)(b * C_IN) + 2 * c2) << 12) + s0 + 4 * v;
  __bf16* xdst = &Xs[0][0] + (4 * v) * ROW2 + 2 * c2;

  // B pointers: wave's 3 otiles (each 32 outs), tiled Wt, lane-coalesced
  const int otb = og * 6 + wn * 3;
  const __bf16* wt0 = Wt + (((size_t)(otb + 0) * 48 + hi) << 8) + col * 8;
  const __bf16* wt1 = Wt + (((size_t)(otb + 1) * 48 + hi) << 8) + col * 8;
  const __bf16* wt2 = Wt + (((size_t)(otb + 2) * 48 + hi) << 8) + col * 8;

  f32x16 acc[3];
#pragma unroll
  for (int n = 0; n < 3; ++n)
#pragma unroll
    for (int r = 0; r < 16; ++r) acc[n][r] = 0.f;

  bf16x4 sA0, sB0, sA1, sB1;   // staging reg sets (step parity)
  bf16x8 bP[6], bQ[6];         // B fragment sets (step parity)

#define SLOAD(sa, sb, K)                                   \
  {                                                        \
    const __bf16* sp_ = xsrc + ((size_t)(K) << 12);        \
    sa = *reinterpret_cast<const bf16x4*>(sp_);            \
    sb = *reinterpret_cast<const bf16x4*>(sp_ + SPB);      \
  }
#define SWRITE(bi, sa, sb)                                 \
  {                                                        \
    __bf16* d_ = xdst + (bi) * (BP * ROW2);                \
    _Pragma("unroll") for (int r_ = 0; r_ < 4; ++r_) {     \
      bf16x2 pr_;                                          \
      pr_[0] = sa[r_];                                     \
      pr_[1] = sb[r_];                                     \
      *reinterpret_cast<bf16x2*>(d_ + r_ * ROW2) = pr_;    \
    }                                                      \
  }
#define LOADB(dst, IT)                                                         \
  {                                                                            \
    const int ko_ = (IT) * 1024;                                               \
    dst[0] = *reinterpret_cast<const bf16x8*>(wt0 + ko_);                      \
    dst[1] = *reinterpret_cast<const bf16x8*>(wt1 + ko_);                      \
    dst[2] = *reinterpret_cast<const bf16x8*>(wt2 + ko_);                      \
    dst[3] = *reinterpret_cast<const bf16x8*>(wt0 + ko_ + 512);                \
    dst[4] = *reinterpret_cast<const bf16x8*>(wt1 + ko_ + 512);                \
    dst[5] = *reinterpret_cast<const bf16x8*>(wt2 + ko_ + 512);                \
  }
#define COMPUTE(bi, bb)                                                             \
  {                                                                                 \
    const __bf16* ap_ = &Xs[0][0] + (bi) * (BP * ROW2) + (wm * 32 + col) * ROW2 + hi * 8; \
    const bf16x8 a0_ = *reinterpret_cast<const bf16x8*>(ap_);                       \
    const bf16x8 a1_ = *reinterpret_cast<const bf16x8*>(ap_ + 16);                  \
    acc[0] = __builtin_amdgcn_mfma_f32_32x32x16_bf16(a0_, bb[0], acc[0], 0, 0, 0);  \
    acc[1] = __builtin_amdgcn_mfma_f32_32x32x16_bf16(a0_, bb[1], acc[1], 0, 0, 0);  \
    acc[2] = __builtin_amdgcn_mfma_f32_32x32x16_bf16(a0_, bb[2], acc[2], 0, 0, 0);  \
    acc[0] = __builtin_amdgcn_mfma_f32_32x32x16_bf16(a1_, bb[3], acc[0], 0, 0, 0);  \
    acc[1] = __builtin_amdgcn_mfma_f32_32x32x16_bf16(a1_, bb[4], acc[1], 0, 0, 0);  \
    acc[2] = __builtin_amdgcn_mfma_f32_32x32x16_bf16(a1_, bb[5], acc[2], 0, 0, 0);  \
  }
#define KBARRIER()                                         \
  {                                                        \
    asm volatile("s_waitcnt lgkmcnt(0)" ::: "memory");     \
    __builtin_amdgcn_s_barrier();                          \
    __builtin_amdgcn_sched_barrier(0);                     \
  }

  // ---- prologue: steps 0,1 loaded; step 0 staged; B(0) in flight ----
  SLOAD(sA0, sB0, 0);
  SLOAD(sA1, sB1, 32);
  SWRITE(0, sA0, sB0);
  LOADB(bP, 0);
  KBARRIER();

  // ---- main k-loop: 12 steps, fully unrolled, raw barriers ----
#pragma unroll
  for (int it = 0; it < 12; ++it) {
    if (it < 11) {  // stage step it+1 (data loaded 1-2 iters ago; set parity (it+1)&1)
      if (it & 1) { SWRITE((it + 1) % 3, sA0, sB0); }
      else        { SWRITE((it + 1) % 3, sA1, sB1); }
    }
    if (it < 10) {  // issue loads for step it+2 (set parity it&1)
      if (it & 1) { SLOAD(sA1, sB1, 32 * (it + 2)); }
      else        { SLOAD(sA0, sB0, 32 * (it + 2)); }
    }
    if (it < 11) {  // prefetch B for step it+1
      if (it & 1) { LOADB(bP, it + 1); }
      else        { LOADB(bQ, it + 1); }
    }
    if (it & 1) { COMPUTE(it % 3, bQ); }
    else        { COMPUTE(it % 3, bP); }
    KBARRIER();
  }
#undef SLOAD
#undef SWRITE
#undef LOADB
#undef COMPUTE
#undef KBARRIER

  // ---- epilogue: LN correction + GELU + non-temporal f32x4 NCHW stores ----
#pragma unroll
  for (int n = 0; n < 3; ++n) {
    const int o = og * 192 + wn * 96 + n * 32 + col;
    const float t1v = t1g[o];
    const float t2v = t2g[o];
    float* op = out + (((size_t)(b * C_OUT + o)) << 12) + s0 + wm * 32;
#pragma unroll
    for (int qd = 0; qd < 4; ++qd) {
      const int pr = qd * 8 + hi * 4;  // px within wave's 32-block
      const f32x4 mu4 = *reinterpret_cast<const f32x4*>(&mu_s[wm * 32 + pr]);
      const f32x4 rs4 = *reinterpret_cast<const f32x4*>(&rs_s[wm * 32 + pr]);
      f32x4 y;
#pragma unroll
      for (int r = 0; r < 4; ++r) {
        const float val = rs4[r] * (acc[n][qd * 4 + r] - mu4[r] * t1v) + t2v;
        y[r] = gelu_fast(val);
      }
      __builtin_nontemporal_store(y, reinterpret_cast<f32x4*>(op + pr));
    }
  }
}

// ---------------------------------------------------------------------------
// Fallback (R4/R5): fully fused single-pass kernel (measured 193 us), used
// only if ws_size can't hold the bf16 x copy.
// ---------------------------------------------------------------------------
__global__ __launch_bounds__(256, 3) void ppl_fused_kernel(const float* __restrict__ x,
                                                           const __bf16* __restrict__ Wp,
                                                           const float* __restrict__ t1g,
                                                           const float* __restrict__ t2g,
                                                           float* __restrict__ out) {
  __shared__ __bf16 Xs[BP][LDK];
  __shared__ float sS[4][BP];
  __shared__ float sQ[4][BP];
  __shared__ float mu_s[BP];
  __shared__ float rs_s[BP];

  const int tid = threadIdx.x;
  const int w = tid >> 6;
  const int lane = tid & 63;
  const int q = tid & 15;
  const int j = tid >> 4;
  const int col = lane & 31;
  const int hi = lane >> 5;
  const int p0 = blockIdx.x * BP;
  const int b = p0 >> 12;
  const int s0 = p0 & 4095;
  const int ob = w * 96;

  const float* xq = x + (size_t)b * (C_IN * SPB) + s0 + 4 * q;

  f32x4 LA[12], LB[12];
#pragma unroll
  for (int i = 0; i < 3; ++i)
#pragma unroll
    for (int m = 0; m < 4; ++m)
      LA[i * 4 + m] = *reinterpret_cast<const f32x4*>(xq + (size_t)(64 * i + 4 * j + m) * SPB);
#pragma unroll
  for (int i = 0; i < 3; ++i)
#pragma unroll
    for (int m = 0; m < 4; ++m)
      LB[i * 4 + m] = *reinterpret_cast<const f32x4*>(xq + (size_t)(64 * (i + 3) + 4 * j + m) * SPB);

  float ss[4] = {0.f, 0.f, 0.f, 0.f};
  float qq[4] = {0.f, 0.f, 0.f, 0.f};

#define PROCESS(L, ibase)                                                   \
  {                                                                         \
    _Pragma("unroll") for (int i = 0; i < 3; ++i) {                         \
      _Pragma("unroll") for (int r = 0; r < 4; ++r) {                       \
        const float f0 = L[i * 4 + 0][r];                                   \
        const float f1 = L[i * 4 + 1][r];                                   \
        const float f2 = L[i * 4 + 2][r];                                   \
        const float f3 = L[i * 4 + 3][r];                                   \
        ss[r] += (f0 + f1) + (f2 + f3);                                     \
        qq[r] += (f0 * f0 + f1 * f1) + (f2 * f2 + f3 * f3);                 \
        bf16x4 pk;                                                          \
        pk[0] = (__bf16)f0; pk[1] = (__bf16)f1;                             \
        pk[2] = (__bf16)f2; pk[3] = (__bf16)f3;                             \
        *reinterpret_cast<bf16x4*>(&Xs[4 * q + r][64 * ((ibase) + i) + 4 * j]) = pk; \
      }                                                                     \
    }                                                                       \
  }
  PROCESS(LA, 0)
  PROCESS(LB, 3)
#undef PROCESS

#pragma unroll
  for (int r = 0; r < 4; ++r) {
    ss[r] += __shfl_xor(ss[r], 16);
    ss[r] += __shfl_xor(ss[r], 32);
    qq[r] += __shfl_xor(qq[r], 16);
    qq[r] += __shfl_xor(qq[r], 32);
  }
  if (lane < 16) {
#pragma unroll
    for (int r = 0; r < 4; ++r) {
      sS[w][4 * lane + r] = ss[r];
      sQ[w][4 * lane + r] = qq[r];
    }
  }
  __syncthreads();
  if (tid < BP) {
    const float st = sS[0][tid] + sS[1][tid] + sS[2][tid] + sS[3][tid];
    const float qt = sQ[0][tid] + sQ[1][tid] + sQ[2][tid] + sQ[3][tid];
    const float m = st * (1.0f / C_IN);
    mu_s[tid] = m;
    rs_s[tid] = rsqrtf(qt * (1.0f / C_IN) - m * m + 1e-5f);
  }
  __syncthreads();

  const __bf16* wp0 = Wp + (size_t)(ob + col) * C_IN + hi * 8;
  const __bf16* wp1 = wp0 + 32 * C_IN;
  const __bf16* wp2 = wp0 + 64 * C_IN;
  const __bf16* xs0 = &Xs[col][hi * 8];
  const __bf16* xs1 = &Xs[32 + col][hi * 8];

  f32x16 acc[2][3];
#pragma unroll
  for (int m = 0; m < 2; ++m)
#pragma unroll
    for (int n = 0; n < 3; ++n)
#pragma unroll
      for (int r = 0; r < 16; ++r) acc[m][n][r] = 0.f;

#define LOADB(dst, kk)                                     \
  {                                                        \
    dst[0] = *reinterpret_cast<const bf16x8*>(wp0 + (kk)); \
    dst[1] = *reinterpret_cast<const bf16x8*>(wp1 + (kk)); \
    dst[2] = *reinterpret_cast<const bf16x8*>(wp2 + (kk)); \
  }
#define STEP(bb, kk)                                                                    \
  {                                                                                     \
    const bf16x8 a0 = *reinterpret_cast<const bf16x8*>(xs0 + (kk));                     \
    const bf16x8 a1 = *reinterpret_cast<const bf16x8*>(xs1 + (kk));                     \
    acc[0][0] = __builtin_amdgcn_mfma_f32_32x32x16_bf16(a0, bb[0], acc[0][0], 0, 0, 0); \
    acc[0][1] = __builtin_amdgcn_mfma_f32_32x32x16_bf16(a0, bb[1], acc[0][1], 0, 0, 0); \
    acc[0][2] = __builtin_amdgcn_mfma_f32_32x32x16_bf16(a0, bb[2], acc[0][2], 0, 0, 0); \
    acc[1][0] = __builtin_amdgcn_mfma_f32_32x32x16_bf16(a1, bb[0], acc[1][0], 0, 0, 0); \
    acc[1][1] = __builtin_amdgcn_mfma_f32_32x32x16_bf16(a1, bb[1], acc[1][1], 0, 0, 0); \
    acc[1][2] = __builtin_amdgcn_mfma_f32_32x32x16_bf16(a1, bb[2], acc[1][2], 0, 0, 0); \
  }
  {
    bf16x8 bA[3], bB[3];
    LOADB(bA, 0);
#pragma unroll
    for (int it = 0; it < 12; ++it) {
      const int k = it * 32;
      LOADB(bB, k + 16);
      STEP(bA, k);
      if (it < 11) LOADB(bA, k + 32);
      STEP(bB, k + 16);
    }
  }
#undef LOADB
#undef STEP

  const float t1v[3] = {t1g[ob + col], t1g[ob + 32 + col], t1g[ob + 64 + col]};
  const float t2v[3] = {t2g[ob + col], t2g[ob + 32 + col], t2g[ob + 64 + col]};
  float* outp = out + (((size_t)(b * C_OUT + ob + col)) << 12) + s0;
#pragma unroll
  for (int nf = 0; nf < 3; ++nf) {
    float* op = outp + ((size_t)nf << 17);
#pragma unroll
    for (int m = 0; m < 2; ++m) {
#pragma unroll
      for (int qd = 0; qd < 4; ++qd) {
        const int pr = m * 32 + qd * 8 + hi * 4;
        const f32x4 mu4 = *reinterpret_cast<const f32x4*>(&mu_s[pr]);
        const f32x4 rs4 = *reinterpret_cast<const f32x4*>(&rs_s[pr]);
        f32x4 y;
#pragma unroll
        for (int r = 0; r < 4; ++r) {
          const float val = rs4[r] * (acc[m][nf][qd * 4 + r] - mu4[r] * t1v[nf]) + t2v[nf];
          y[r] = gelu_fast(val);
        }
        *reinterpret_cast<f32x4*>(op + pr) = y;
      }
    }
  }
}

// ---------------------------------------------------------------------------
extern "C" void kernel_launch(void* const* d_in, const int* in_sizes, int n_in,
                              void* d_out, int out_size, void* d_ws, size_t ws_size,
                              hipStream_t stream) {
  const float* x = (const float*)d_in[0];
  const float* gamma = (const float*)d_in[1];
  const float* beta = (const float*)d_in[2];
  const float* W = (const float*)d_in[3];
  const float* bias = (const float*)d_in[4];
  float* out = (float*)d_out;

  // workspace layout
  __bf16* Wp = (__bf16*)d_ws;                   // 294912 B (row-major, fallback)
  __bf16* Wt = Wp + C_OUT * C_IN;               // 294912 B (tiled, gemm)
  float* t1 = (float*)(Wt + C_OUT * C_IN);      // 1536 B
  float* t2 = t1 + C_OUT;                       // 1536 B
  float* mu = t2 + C_OUT;                       // NPIX floats
  float* rs = mu + NPIX;                        // NPIX floats
  __bf16* xb = (__bf16*)(rs + NPIX);            // NPIX * C_IN bf16 = 100.7 MB

  const size_t need = 2 * (size_t)C_OUT * C_IN * 2 + 2 * C_OUT * 4 +
                      2 * (size_t)NPIX * 4 + (size_t)NPIX * C_IN * 2;

  ppl_prep_kernel<<<C_OUT, 128, 0, stream>>>(W, gamma, beta, bias, Wp, Wt, t1, t2);

  if (ws_size >= need) {
    ppl_stats_cast_kernel<<<NPIX / 256, 512, 0, stream>>>(x, xb, mu, rs);
    ppl_gemm4_kernel<<<(NPIX / BP) * 2, 256, 0, stream>>>(xb, Wt, mu, rs, t1, t2, out);
  } else {
    ppl_fused_kernel<<<NPIX / BP, 256, 0, stream>>>(x, Wp, t1, t2, out);
  }
}

// Round 9
// 194.427 us; speedup vs baseline: 1.1760x; 1.1760x over previous
//
#include <hip/hip_runtime.h>
#include <hip/hip_bf16.h>
#include <cmath>

typedef float f32x4 __attribute__((ext_vector_type(4)));
typedef float f32x16 __attribute__((ext_vector_type(16)));
typedef __bf16 bf16x2 __attribute__((ext_vector_type(2)));
typedef __bf16 bf16x4 __attribute__((ext_vector_type(4)));
typedef __bf16 bf16x8 __attribute__((ext_vector_type(8)));

#define C_IN 384
#define C_OUT 384
#define SPB 4096      // spatial per batch image (64*64)
#define NPIX 131072   // 32 * 4096 total pixels
#define BP 64         // pixels per GEMM block
#define LDK 392       // fallback kernel's padded Xs row
#define P1ROW 36      // pass1 [c][px] LDS row stride in bf16 (72 B)

// ---------------------------------------------------------------------------
// prep: Wp[o][c] = bf16(W[o][c]*gamma[c])  (row-major, for fallback)
//       Wt tiled: Wt[((o>>5)*48 + (c>>3))*256 + (o&31)*8 + (c&7)]  (for gemm)
//       t1[o] = sum_c float(Wp[o][c]);  t2[o] = sum_c beta[c]*W[o][c] + b[o]
// ---------------------------------------------------------------------------
__global__ __launch_bounds__(128) void ppl_prep_kernel(const float* __restrict__ W,
                                                       const float* __restrict__ gamma,
                                                       const float* __restrict__ beta,
                                                       const float* __restrict__ bias,
                                                       __bf16* __restrict__ Wp,
                                                       __bf16* __restrict__ Wt,
                                                       float* __restrict__ t1,
                                                       float* __restrict__ t2) {
  const int o = blockIdx.x;
  const int t = threadIdx.x;
  const float* row = W + o * C_IN;
  float s1 = 0.f, s2 = 0.f;
  for (int c = t; c < C_IN; c += 128) {
    const float w = row[c];
    const __bf16 wq = (__bf16)(w * gamma[c]);
    Wp[o * C_IN + c] = wq;
    Wt[(((size_t)(o >> 5) * 48 + (c >> 3)) << 8) + ((o & 31) << 3) + (c & 7)] = wq;
    s1 += (float)wq;
    s2 += beta[c] * w;
  }
#pragma unroll
  for (int off = 32; off > 0; off >>= 1) {
    s1 += __shfl_down(s1, off);
    s2 += __shfl_down(s2, off);
  }
  __shared__ float red[2][2];
  if ((t & 63) == 0) { red[t >> 6][0] = s1; red[t >> 6][1] = s2; }
  __syncthreads();
  if (t == 0) {
    t1[o] = red[0][0] + red[1][0];
    t2[o] = red[0][1] + red[1][1] + bias[o];
  }
}

// fast GELU: tanh-form via sigmoid; validated R2-R7 (absmax unchanged at 0.0156)
__device__ __forceinline__ float gelu_fast(float v) {
  const float u = 0.7978845608028654f * v * __builtin_fmaf(0.044715f * v, v, 1.0f);
  const float e = __expf(-2.0f * u);
  return v * __builtin_amdgcn_rcpf(1.0f + e);
}

// ---------------------------------------------------------------------------
// Pass 1: LN stats + bf16 cast + A-FRAGMENT layout transpose.
//   Block = 32 px x all 384 ch, 256 threads, grid 4096 (streaming shape).
//   Loads: float4 along s (coalesced 128 B segments).  LDS tile [c][px]
//   (b64 contiguous writes).  Output xT in exact MFMA A-fragment order:
//   frag (g, kt, h): lane l holds px=g*32+(l&31), c=32kt+16h+8*(l>>5)+j
//   -> per-wave 1024 B contiguous stores.  GEMM then needs no LDS/barriers.
// ---------------------------------------------------------------------------
__global__ __launch_bounds__(256) void ppl_stats_frag_kernel(const float* __restrict__ x,
                                                             __bf16* __restrict__ xT,
                                                             float* __restrict__ mu,
                                                             float* __restrict__ rs) {
  __shared__ __bf16 Xc[C_IN * P1ROW];  // 27648 B, [c][px]
  __shared__ float sS[4][8][4];
  __shared__ float sQ[4][8][4];

  const int tid = threadIdx.x;
  const int q = tid & 7;        // pixel quad base 4q
  const int cg = tid >> 3;      // channel residue 0..31
  const int g = blockIdx.x;     // 32-px group id
  const int p0 = g * 32;
  const int b = p0 >> 12;
  const int s0 = p0 & 4095;

  const float* xp = x + (((size_t)(b * C_IN + cg)) << 12) + s0 + 4 * q;

  // 12 float4 loads (channels cg, cg+32, ..., cg+352), all issued up-front
  f32x4 L[12];
#pragma unroll
  for (int ch = 0; ch < 12; ++ch)
    L[ch] = *reinterpret_cast<const f32x4*>(xp + (((size_t)ch * 32) << 12));

  f32x4 ssv = {0.f, 0.f, 0.f, 0.f};
  f32x4 qqv = {0.f, 0.f, 0.f, 0.f};
#pragma unroll
  for (int ch = 0; ch < 12; ++ch) {
    const f32x4 v = L[ch];
    ssv += v;
    qqv += v * v;
    bf16x4 pk;
    pk[0] = (__bf16)v[0];
    pk[1] = (__bf16)v[1];
    pk[2] = (__bf16)v[2];
    pk[3] = (__bf16)v[3];
    *reinterpret_cast<bf16x4*>(&Xc[(ch * 32 + cg) * P1ROW + 4 * q]) = pk;
  }

  // stats reduce over cg: shfl over lane bits 3-5 (cg within wave), LDS across waves
#pragma unroll
  for (int r = 0; r < 4; ++r) {
    ssv[r] += __shfl_xor(ssv[r], 8);
    ssv[r] += __shfl_xor(ssv[r], 16);
    ssv[r] += __shfl_xor(ssv[r], 32);
    qqv[r] += __shfl_xor(qqv[r], 8);
    qqv[r] += __shfl_xor(qqv[r], 16);
    qqv[r] += __shfl_xor(qqv[r], 32);
  }
  const int wv = tid >> 6;
  const int lane = tid & 63;
  if (lane < 8) {
#pragma unroll
    for (int r = 0; r < 4; ++r) {
      sS[wv][lane][r] = ssv[r];
      sQ[wv][lane][r] = qqv[r];
    }
  }
  __syncthreads();
  if (tid < 32) {
    const int qq_ = tid >> 2, rr_ = tid & 3;
    const float st = sS[0][qq_][rr_] + sS[1][qq_][rr_] + sS[2][qq_][rr_] + sS[3][qq_][rr_];
    const float qt = sQ[0][qq_][rr_] + sQ[1][qq_][rr_] + sQ[2][qq_][rr_] + sQ[3][qq_][rr_];
    const float m = st * (1.0f / C_IN);
    mu[p0 + tid] = m;
    rs[p0 + tid] = rsqrtf(qt * (1.0f / C_IN) - m * m + 1e-5f);
  }

  // fragment write: wave wv handles frag indices f = wv*6 .. wv*6+5 (f = kt*2+h)
  const int px = lane & 31;
  const int oct = lane >> 5;
  __bf16* xto = xT + (size_t)g * 12288 + lane * 8;
#pragma unroll
  for (int i = 0; i < 6; ++i) {
    const int f = wv * 6 + i;
    const int cb = (f >> 1) * 32 + (f & 1) * 16 + oct * 8;
    bf16x8 frag;
#pragma unroll
    for (int j = 0; j < 8; ++j) frag[j] = Xc[(cb + j) * P1ROW + px];
    *reinterpret_cast<bf16x8*>(xto + (size_t)f * 512) = frag;
  }
}

// ---------------------------------------------------------------------------
// Pass 2 (gemm5): barrier-free, LDS-free GEMM + LN epilogue + GELU.
//   Block = 64 px x 192 outs, grid 4096.  A-frags: single coalesced 16B/lane
//   loads from fragment-layout xT (L3-resident), 3-step register ring.
//   B-frags: tiled Wt from L2, 2-set ping-pong 2 steps ahead.  No barriers:
//   12 waves/CU free-run and hide latency independently.  Regular stores
//   (nt stores caused 2.1x write amplification in R7 -- reverted).
// ---------------------------------------------------------------------------
__global__ __launch_bounds__(256, 3) void ppl_gemm5_kernel(const __bf16* __restrict__ xT,
                                                           const __bf16* __restrict__ Wt,
                                                           const float* __restrict__ mug,
                                                           const float* __restrict__ rsg,
                                                           const float* __restrict__ t1g,
                                                           const float* __restrict__ t2g,
                                                           float* __restrict__ out) {
  const int tid = threadIdx.x;
  const int w = tid >> 6;
  const int lane = tid & 63;
  const int col = lane & 31;
  const int hi = lane >> 5;
  const int wm = w >> 1;          // px half -> fragment group
  const int wn = w & 1;           // out half (96 outs)
  const int bid = blockIdx.x;
  const int og = bid & 1;         // out group (192 outs)
  const int pt = bid >> 1;
  const int p0 = pt * BP;
  const int b = p0 >> 12;
  const int s0 = p0 & 4095;
  const int g = pt * 2 + wm;

  const __bf16* aptr = xT + (size_t)g * 12288 + lane * 8;
  const int otb = og * 6 + wn * 3;
  const __bf16* wt0 = Wt + (((size_t)(otb + 0) * 48 + hi) << 8) + col * 8;
  const __bf16* wt1 = Wt + (((size_t)(otb + 1) * 48 + hi) << 8) + col * 8;
  const __bf16* wt2 = Wt + (((size_t)(otb + 2) * 48 + hi) << 8) + col * 8;

  f32x16 acc[3];
#pragma unroll
  for (int n = 0; n < 3; ++n)
#pragma unroll
    for (int r = 0; r < 16; ++r) acc[n][r] = 0.f;

  bf16x8 aF0[3], aF1[3];   // A fragment ring, 3 steps deep
  bf16x8 bS0[6], bS1[6];   // B fragment sets, ping-pong (2 steps ahead)

#define ALOAD(d, kt)                                                        \
  {                                                                         \
    aF0[d] = *reinterpret_cast<const bf16x8*>(aptr + (kt) * 1024);          \
    aF1[d] = *reinterpret_cast<const bf16x8*>(aptr + (kt) * 1024 + 512);    \
  }
#define BLOAD(arr, kt)                                                      \
  {                                                                         \
    const int ko_ = (kt) * 1024;                                            \
    arr[0] = *reinterpret_cast<const bf16x8*>(wt0 + ko_);                   \
    arr[1] = *reinterpret_cast<const bf16x8*>(wt1 + ko_);                   \
    arr[2] = *reinterpret_cast<const bf16x8*>(wt2 + ko_);                   \
    arr[3] = *reinterpret_cast<const bf16x8*>(wt0 + ko_ + 512);             \
    arr[4] = *reinterpret_cast<const bf16x8*>(wt1 + ko_ + 512);             \
    arr[5] = *reinterpret_cast<const bf16x8*>(wt2 + ko_ + 512);             \
  }
#define CSTEP(d, arr)                                                               \
  {                                                                                 \
    acc[0] = __builtin_amdgcn_mfma_f32_32x32x16_bf16(aF0[d], arr[0], acc[0], 0, 0, 0); \
    acc[1] = __builtin_amdgcn_mfma_f32_32x32x16_bf16(aF0[d], arr[1], acc[1], 0, 0, 0); \
    acc[2] = __builtin_amdgcn_mfma_f32_32x32x16_bf16(aF0[d], arr[2], acc[2], 0, 0, 0); \
    acc[0] = __builtin_amdgcn_mfma_f32_32x32x16_bf16(aF1[d], arr[3], acc[0], 0, 0, 0); \
    acc[1] = __builtin_amdgcn_mfma_f32_32x32x16_bf16(aF1[d], arr[4], acc[1], 0, 0, 0); \
    acc[2] = __builtin_amdgcn_mfma_f32_32x32x16_bf16(aF1[d], arr[5], acc[2], 0, 0, 0); \
  }

  // prologue: A 3 deep, B 2 deep
  ALOAD(0, 0);
  ALOAD(1, 1);
  ALOAD(2, 2);
  BLOAD(bS0, 0);
  BLOAD(bS1, 1);

#pragma unroll
  for (int it = 0; it < 12; ++it) {
    if (it & 1) { CSTEP(it % 3, bS1); }
    else        { CSTEP(it % 3, bS0); }
    if (it + 3 < 12) ALOAD(it % 3, it + 3);
    if (it + 2 < 12) {
      if (it & 1) { BLOAD(bS1, it + 2); }
      else        { BLOAD(bS0, it + 2); }
    }
  }
#undef ALOAD
#undef BLOAD
#undef CSTEP

  // ---- epilogue: LN correction + GELU + regular f32x4 NCHW stores ----
#pragma unroll
  for (int n = 0; n < 3; ++n) {
    const int o = og * 192 + wn * 96 + n * 32 + col;
    const float t1v = t1g[o];
    const float t2v = t2g[o];
    float* op = out + (((size_t)(b * C_OUT + o)) << 12) + s0 + wm * 32;
#pragma unroll
    for (int qd = 0; qd < 4; ++qd) {
      const int pr = qd * 8 + hi * 4;  // px within wave's 32-block
      const f32x4 mu4 = *reinterpret_cast<const f32x4*>(mug + p0 + wm * 32 + pr);
      const f32x4 rs4 = *reinterpret_cast<const f32x4*>(rsg + p0 + wm * 32 + pr);
      f32x4 y;
#pragma unroll
      for (int r = 0; r < 4; ++r) {
        const float val = rs4[r] * (acc[n][qd * 4 + r] - mu4[r] * t1v) + t2v;
        y[r] = gelu_fast(val);
      }
      *reinterpret_cast<f32x4*>(op + pr) = y;
    }
  }
}

// ---------------------------------------------------------------------------
// Fallback (R4/R5): fully fused single-pass kernel (measured 193 us), used
// only if ws_size can't hold the bf16 x copy.
// ---------------------------------------------------------------------------
__global__ __launch_bounds__(256, 3) void ppl_fused_kernel(const float* __restrict__ x,
                                                           const __bf16* __restrict__ Wp,
                                                           const float* __restrict__ t1g,
                                                           const float* __restrict__ t2g,
                                                           float* __restrict__ out) {
  __shared__ __bf16 Xs[BP][LDK];
  __shared__ float sS[4][BP];
  __shared__ float sQ[4][BP];
  __shared__ float mu_s[BP];
  __shared__ float rs_s[BP];

  const int tid = threadIdx.x;
  const int w = tid >> 6;
  const int lane = tid & 63;
  const int q = tid & 15;
  const int j = tid >> 4;
  const int col = lane & 31;
  const int hi = lane >> 5;
  const int p0 = blockIdx.x * BP;
  const int b = p0 >> 12;
  const int s0 = p0 & 4095;
  const int ob = w * 96;

  const float* xq = x + (size_t)b * (C_IN * SPB) + s0 + 4 * q;

  f32x4 LA[12], LB[12];
#pragma unroll
  for (int i = 0; i < 3; ++i)
#pragma unroll
    for (int m = 0; m < 4; ++m)
      LA[i * 4 + m] = *reinterpret_cast<const f32x4*>(xq + (size_t)(64 * i + 4 * j + m) * SPB);
#pragma unroll
  for (int i = 0; i < 3; ++i)
#pragma unroll
    for (int m = 0; m < 4; ++m)
      LB[i * 4 + m] = *reinterpret_cast<const f32x4*>(xq + (size_t)(64 * (i + 3) + 4 * j + m) * SPB);

  float ss[4] = {0.f, 0.f, 0.f, 0.f};
  float qq[4] = {0.f, 0.f, 0.f, 0.f};

#define PROCESS(L, ibase)                                                   \
  {                                                                         \
    _Pragma("unroll") for (int i = 0; i < 3; ++i) {                         \
      _Pragma("unroll") for (int r = 0; r < 4; ++r) {                       \
        const float f0 = L[i * 4 + 0][r];                                   \
        const float f1 = L[i * 4 + 1][r];                                   \
        const float f2 = L[i * 4 + 2][r];                                   \
        const float f3 = L[i * 4 + 3][r];                                   \
        ss[r] += (f0 + f1) + (f2 + f3);                                     \
        qq[r] += (f0 * f0 + f1 * f1) + (f2 * f2 + f3 * f3);                 \
        bf16x4 pk;                                                          \
        pk[0] = (__bf16)f0; pk[1] = (__bf16)f1;                             \
        pk[2] = (__bf16)f2; pk[3] = (__bf16)f3;                             \
        *reinterpret_cast<bf16x4*>(&Xs[4 * q + r][64 * ((ibase) + i) + 4 * j]) = pk; \
      }                                                                     \
    }                                                                       \
  }
  PROCESS(LA, 0)
  PROCESS(LB, 3)
#undef PROCESS

#pragma unroll
  for (int r = 0; r < 4; ++r) {
    ss[r] += __shfl_xor(ss[r], 16);
    ss[r] += __shfl_xor(ss[r], 32);
    qq[r] += __shfl_xor(qq[r], 16);
    qq[r] += __shfl_xor(qq[r], 32);
  }
  if (lane < 16) {
#pragma unroll
    for (int r = 0; r < 4; ++r) {
      sS[w][4 * lane + r] = ss[r];
      sQ[w][4 * lane + r] = qq[r];
    }
  }
  __syncthreads();
  if (tid < BP) {
    const float st = sS[0][tid] + sS[1][tid] + sS[2][tid] + sS[3][tid];
    const float qt = sQ[0][tid] + sQ[1][tid] + sQ[2][tid] + sQ[3][tid];
    const float m = st * (1.0f / C_IN);
    mu_s[tid] = m;
    rs_s[tid] = rsqrtf(qt * (1.0f / C_IN) - m * m + 1e-5f);
  }
  __syncthreads();

  const __bf16* wp0 = Wp + (size_t)(ob + col) * C_IN + hi * 8;
  const __bf16* wp1 = wp0 + 32 * C_IN;
  const __bf16* wp2 = wp0 + 64 * C_IN;
  const __bf16* xs0 = &Xs[col][hi * 8];
  const __bf16* xs1 = &Xs[32 + col][hi * 8];

  f32x16 acc[2][3];
#pragma unroll
  for (int m = 0; m < 2; ++m)
#pragma unroll
    for (int n = 0; n < 3; ++n)
#pragma unroll
      for (int r = 0; r < 16; ++r) acc[m][n][r] = 0.f;

#define LOADB(dst, kk)                                     \
  {                                                        \
    dst[0] = *reinterpret_cast<const bf16x8*>(wp0 + (kk)); \
    dst[1] = *reinterpret_cast<const bf16x8*>(wp1 + (kk)); \
    dst[2] = *reinterpret_cast<const bf16x8*>(wp2 + (kk)); \
  }
#define STEP(bb, kk)                                                                    \
  {                                                                                     \
    const bf16x8 a0 = *reinterpret_cast<const bf16x8*>(xs0 + (kk));                     \
    const bf16x8 a1 = *reinterpret_cast<const bf16x8*>(xs1 + (kk));                     \
    acc[0][0] = __builtin_amdgcn_mfma_f32_32x32x16_bf16(a0, bb[0], acc[0][0], 0, 0, 0); \
    acc[0][1] = __builtin_amdgcn_mfma_f32_32x32x16_bf16(a0, bb[1], acc[0][1], 0, 0, 0); \
    acc[0][2] = __builtin_amdgcn_mfma_f32_32x32x16_bf16(a0, bb[2], acc[0][2], 0, 0, 0); \
    acc[1][0] = __builtin_amdgcn_mfma_f32_32x32x16_bf16(a1, bb[0], acc[1][0], 0, 0, 0); \
    acc[1][1] = __builtin_amdgcn_mfma_f32_32x32x16_bf16(a1, bb[1], acc[1][1], 0, 0, 0); \
    acc[1][2] = __builtin_amdgcn_mfma_f32_32x32x16_bf16(a1, bb[2], acc[1][2], 0, 0, 0); \
  }
  {
    bf16x8 bA[3], bB[3];
    LOADB(bA, 0);
#pragma unroll
    for (int it = 0; it < 12; ++it) {
      const int k = it * 32;
      LOADB(bB, k + 16);
      STEP(bA, k);
      if (it < 11) LOADB(bA, k + 32);
      STEP(bB, k + 16);
    }
  }
#undef LOADB
#undef STEP

  const float t1v[3] = {t1g[ob + col], t1g[ob + 32 + col], t1g[ob + 64 + col]};
  const float t2v[3] = {t2g[ob + col], t2g[ob + 32 + col], t2g[ob + 64 + col]};
  float* outp = out + (((size_t)(b * C_OUT + ob + col)) << 12) + s0;
#pragma unroll
  for (int nf = 0; nf < 3; ++nf) {
    float* op = outp + ((size_t)nf << 17);
#pragma unroll
    for (int m = 0; m < 2; ++m) {
#pragma unroll
      for (int qd = 0; qd < 4; ++qd) {
        const int pr = m * 32 + qd * 8 + hi * 4;
        const f32x4 mu4 = *reinterpret_cast<const f32x4*>(&mu_s[pr]);
        const f32x4 rs4 = *reinterpret_cast<const f32x4*>(&rs_s[pr]);
        f32x4 y;
#pragma unroll
        for (int r = 0; r < 4; ++r) {
          const float val = rs4[r] * (acc[m][nf][qd * 4 + r] - mu4[r] * t1v[nf]) + t2v[nf];
          y[r] = gelu_fast(val);
        }
        *reinterpret_cast<f32x4*>(op + pr) = y;
      }
    }
  }
}

// ---------------------------------------------------------------------------
extern "C" void kernel_launch(void* const* d_in, const int* in_sizes, int n_in,
                              void* d_out, int out_size, void* d_ws, size_t ws_size,
                              hipStream_t stream) {
  const float* x = (const float*)d_in[0];
  const float* gamma = (const float*)d_in[1];
  const float* beta = (const float*)d_in[2];
  const float* W = (const float*)d_in[3];
  const float* bias = (const float*)d_in[4];
  float* out = (float*)d_out;

  // workspace layout
  __bf16* Wp = (__bf16*)d_ws;                   // 294912 B (row-major, fallback)
  __bf16* Wt = Wp + C_OUT * C_IN;               // 294912 B (tiled, gemm)
  float* t1 = (float*)(Wt + C_OUT * C_IN);      // 1536 B
  float* t2 = t1 + C_OUT;                       // 1536 B
  float* mu = t2 + C_OUT;                       // NPIX floats
  float* rs = mu + NPIX;                        // NPIX floats
  __bf16* xT = (__bf16*)(rs + NPIX);            // NPIX * C_IN bf16 = 100.7 MB (fragment layout)

  const size_t need = 2 * (size_t)C_OUT * C_IN * 2 + 2 * C_OUT * 4 +
                      2 * (size_t)NPIX * 4 + (size_t)NPIX * C_IN * 2;

  ppl_prep_kernel<<<C_OUT, 128, 0, stream>>>(W, gamma, beta, bias, Wp, Wt, t1, t2);

  if (ws_size >= need) {
    ppl_stats_frag_kernel<<<NPIX / 32, 256, 0, stream>>>(x, xT, mu, rs);
    ppl_gemm5_kernel<<<(NPIX / BP) * 2, 256, 0, stream>>>(xT, Wt, mu, rs, t1, t2, out);
  } else {
    ppl_fused_kernel<<<NPIX / BP, 256, 0, stream>>>(x, Wp, t1, t2, out);
  }
}